// Round 2
// baseline (1238.632 us; speedup 1.0000x reference)
//
#include <hip/hip_runtime.h>
#include <hip/hip_bf16.h>

#define NN 100000
#define NE 3200000
#define FIN 128
#define HD 16
#define CD 2

// ---- init: deg=1 (self-loop), zero agg1 [N*16], zero agg2 [N*2] ----
__global__ void k_init(float* __restrict__ deg, float* __restrict__ agg1,
                       float* __restrict__ agg2) {
    int i = blockIdx.x * 256 + threadIdx.x;
    if (i < NN * HD) agg1[i] = 0.f;
    if (i < NN) deg[i] = 1.0f;
    if (i < NN * CD) agg2[i] = 0.f;
}

// ---- degree from dst ----
__global__ void k_deg(const int* __restrict__ dst, float* __restrict__ deg) {
    int e = blockIdx.x * 256 + threadIdx.x;
    if (e < NE) atomicAdd(&deg[dst[e]], 1.0f);
}

// ---- dinv = rsqrt(deg), in place ----
__global__ void k_dinv(float* __restrict__ deg) {
    int i = blockIdx.x * 256 + threadIdx.x;
    if (i < NN) deg[i] = rsqrtf(deg[i]);
}

// ---- h1 = x @ W1 (f32 vector ALU): 4 threads/node, 4 outputs each ----
__global__ __launch_bounds__(256) void k_gemm1(const float* __restrict__ x,
                                               const float* __restrict__ W1,
                                               float* __restrict__ h1) {
    __shared__ float wsm[FIN][HD];   // 8 KB, row = k, col = out feature
    for (int i = threadIdx.x; i < FIN * HD; i += 256) wsm[i >> 4][i & 15] = W1[i];
    __syncthreads();
    int t = blockIdx.x * 256 + threadIdx.x;
    int node = t >> 2;
    if (node >= NN) return;
    int g = (t & 3) * 4;             // output group: 0,4,8,12
    const float4* xr = (const float4*)(x + (size_t)node * FIN);
    float a0 = 0.f, a1 = 0.f, a2 = 0.f, a3 = 0.f;
    #pragma unroll
    for (int k4 = 0; k4 < FIN / 4; ++k4) {
        float4 v = xr[k4];
        #pragma unroll
        for (int kk = 0; kk < 4; ++kk) {
            float vk = (kk == 0) ? v.x : (kk == 1) ? v.y : (kk == 2) ? v.z : v.w;
            float4 w = *(const float4*)&wsm[k4 * 4 + kk][g];   // ds_read_b128, broadcast
            a0 += vk * w.x;
            a1 += vk * w.y;
            a2 += vk * w.z;
            a3 += vk * w.w;
        }
    }
    float4 r = {a0, a1, a2, a3};
    *(float4*)(h1 + (size_t)node * HD + g) = r;
}

// ---- scatter layer 1: 4 threads/edge, each handles 4 features ----
__global__ void k_scatter1(const int* __restrict__ src, const int* __restrict__ dst,
                           const float* __restrict__ dinv, const float* __restrict__ h1,
                           float* __restrict__ agg1) {
    int t = blockIdx.x * 256 + threadIdx.x;
    int e = t >> 2;
    if (e >= NE) return;
    int q = t & 3;
    int s = src[e], d = dst[e];
    float norm = dinv[s] * dinv[d];
    float4 hv = *(const float4*)(h1 + (size_t)s * HD + q * 4);
    float* ap = agg1 + (size_t)d * HD + q * 4;
    atomicAdd(ap + 0, hv.x * norm);
    atomicAdd(ap + 1, hv.y * norm);
    atomicAdd(ap + 2, hv.z * norm);
    atomicAdd(ap + 3, hv.w * norm);
}

// ---- epilogue 1: h2 = relu(agg1 + h1*dinv^2 + b1), in place on agg1 ----
__global__ void k_finish1(const float* __restrict__ h1, const float* __restrict__ dinv,
                          const float* __restrict__ b1, float* __restrict__ agg1) {
    int t = blockIdx.x * 256 + threadIdx.x;
    if (t >= NN * HD) return;
    int i = t >> 4, f = t & 15;
    float di = dinv[i];
    float v = agg1[t] + h1[t] * di * di + b1[f];
    agg1[t] = fmaxf(v, 0.f);
}

// ---- g = h2 @ W2 : one thread per node, 16x2 ----
__global__ void k_gemm2(const float* __restrict__ h2, const float* __restrict__ W2,
                        float* __restrict__ g) {
    int i = blockIdx.x * 256 + threadIdx.x;
    if (i >= NN) return;
    const float* hr = h2 + (size_t)i * HD;
    float a0 = 0.f, a1 = 0.f;
    #pragma unroll
    for (int k = 0; k < HD; ++k) {
        float h = hr[k];
        a0 += h * W2[k * 2];
        a1 += h * W2[k * 2 + 1];
    }
    g[(size_t)i * 2]     = a0;
    g[(size_t)i * 2 + 1] = a1;
}

// ---- scatter layer 2: one thread per edge, 2 features ----
__global__ void k_scatter2(const int* __restrict__ src, const int* __restrict__ dst,
                           const float* __restrict__ dinv, const float* __restrict__ g,
                           float* __restrict__ agg2) {
    int e = blockIdx.x * 256 + threadIdx.x;
    if (e >= NE) return;
    int s = src[e], d = dst[e];
    float norm = dinv[s] * dinv[d];
    float2 gv = *(const float2*)(g + (size_t)s * 2);
    atomicAdd(agg2 + (size_t)d * 2,     gv.x * norm);
    atomicAdd(agg2 + (size_t)d * 2 + 1, gv.y * norm);
}

// ---- epilogue 2: + self-loop + b2, log_softmax, f32 out ----
__global__ void k_finish2(const float* __restrict__ g, const float* __restrict__ dinv,
                          const float* __restrict__ b2, const float* __restrict__ agg2,
                          float* __restrict__ out) {
    int i = blockIdx.x * 256 + threadIdx.x;
    if (i >= NN) return;
    float di = dinv[i];
    float sl = di * di;
    float o0 = agg2[(size_t)i * 2]     + g[(size_t)i * 2]     * sl + b2[0];
    float o1 = agg2[(size_t)i * 2 + 1] + g[(size_t)i * 2 + 1] * sl + b2[1];
    float mx = fmaxf(o0, o1);
    float l = mx + logf(__expf(o0 - mx) + __expf(o1 - mx));
    out[(size_t)i * 2]     = o0 - l;
    out[(size_t)i * 2 + 1] = o1 - l;
}

extern "C" void kernel_launch(void* const* d_in, const int* in_sizes, int n_in,
                              void* d_out, int out_size, void* d_ws, size_t ws_size,
                              hipStream_t stream) {
    const float* x   = (const float*)d_in[0];
    const int* ei    = (const int*)d_in[1];
    const int* src   = ei;
    const int* dst   = ei + NE;
    const float* W1  = (const float*)d_in[2];
    const float* b1  = (const float*)d_in[3];
    const float* W2  = (const float*)d_in[4];
    const float* b2  = (const float*)d_in[5];
    float* out = (float*)d_out;

    float* ws   = (float*)d_ws;
    float* deg  = ws;                 // N   (becomes dinv in place)
    float* h1   = ws + NN;            // 16N
    float* agg1 = ws + 17 * NN;       // 16N (becomes h2 in place)
    float* g    = ws + 33 * NN;       // 2N
    float* agg2 = ws + 35 * NN;       // 2N   => 37N floats = 14.8 MB

    k_init<<<(NN * HD + 255) / 256, 256, 0, stream>>>(deg, agg1, agg2);
    k_deg<<<(NE + 255) / 256, 256, 0, stream>>>(dst, deg);
    k_dinv<<<(NN + 255) / 256, 256, 0, stream>>>(deg);
    k_gemm1<<<(NN * 4 + 255) / 256, 256, 0, stream>>>(x, W1, h1);
    k_scatter1<<<(NE * 4 + 255) / 256, 256, 0, stream>>>(src, dst, deg, h1, agg1);
    k_finish1<<<(NN * HD + 255) / 256, 256, 0, stream>>>(h1, deg, b1, agg1);
    k_gemm2<<<(NN + 255) / 256, 256, 0, stream>>>(agg1, W2, g);
    k_scatter2<<<(NE + 255) / 256, 256, 0, stream>>>(src, dst, deg, g, agg2);
    k_finish2<<<(NN + 255) / 256, 256, 0, stream>>>(g, deg, b2, agg2, out);
}

// Round 3
// 925.718 us; speedup vs baseline: 1.3380x; 1.3380x over previous
//
#include <hip/hip_runtime.h>
#include <hip/hip_bf16.h>

#define NN 100000
#define NE 3200000
#define FIN 128
#define HD 16
#define CD 2

// ---- zero the degree histogram ----
__global__ void k_zero(int* __restrict__ cnt) {
    int i = blockIdx.x * 256 + threadIdx.x;
    if (i < NN) cnt[i] = 0;
}

// ---- histogram of dst (in-degree, excluding self-loop) ----
__global__ void k_hist(const int* __restrict__ dst, int* __restrict__ cnt) {
    int e = blockIdx.x * 256 + threadIdx.x;
    if (e < NE) atomicAdd(&cnt[dst[e]], 1);
}

// ---- single-block scan: rowptr (exclusive), next=rowptr copy, dinv=rsqrt(cnt+1) ----
__global__ __launch_bounds__(1024) void k_scan(const int* __restrict__ cnt,
                                               int* __restrict__ rowptr,
                                               int* __restrict__ next,
                                               float* __restrict__ dinv) {
    __shared__ int partial[1024];
    int t = threadIdx.x;
    const int CH = (NN + 1023) / 1024;   // 98
    int base = t * CH;
    int s = 0;
    for (int j = 0; j < CH; ++j) {
        int i = base + j;
        if (i < NN) s += cnt[i];
    }
    partial[t] = s;
    __syncthreads();
    // Hillis-Steele inclusive scan over 1024 partials
    for (int off = 1; off < 1024; off <<= 1) {
        int v = 0;
        if (t >= off) v = partial[t - off];
        __syncthreads();
        if (t >= off) partial[t] += v;
        __syncthreads();
    }
    int excl = (t == 0) ? 0 : partial[t - 1];
    for (int j = 0; j < CH; ++j) {
        int i = base + j;
        if (i < NN) {
            rowptr[i] = excl;
            next[i] = excl;
            int c = cnt[i];
            excl += c;
            dinv[i] = rsqrtf((float)c + 1.0f);
        }
    }
    if (t == 1023) rowptr[NN] = excl;    // = NE
}

// ---- CSR fill: csr[pos] = src, pos via int atomic on next[] ----
__global__ void k_fill(const int* __restrict__ src, const int* __restrict__ dst,
                       int* __restrict__ next, int* __restrict__ csr) {
    int e = blockIdx.x * 256 + threadIdx.x;
    if (e >= NE) return;
    int d = dst[e];
    int pos = atomicAdd(&next[d], 1);
    csr[pos] = src[e];
}

// ---- h1s = (x @ W1) * dinv[node] : 4 threads/node, 4 outputs each ----
__global__ __launch_bounds__(256) void k_gemm1(const float* __restrict__ x,
                                               const float* __restrict__ W1,
                                               const float* __restrict__ dinv,
                                               float* __restrict__ h1s) {
    __shared__ float wsm[FIN][HD];   // 8 KB
    for (int i = threadIdx.x; i < FIN * HD; i += 256) wsm[i >> 4][i & 15] = W1[i];
    __syncthreads();
    int t = blockIdx.x * 256 + threadIdx.x;
    int node = t >> 2;
    if (node >= NN) return;
    int g = (t & 3) * 4;
    const float4* xr = (const float4*)(x + (size_t)node * FIN);
    float a0 = 0.f, a1 = 0.f, a2 = 0.f, a3 = 0.f;
    #pragma unroll
    for (int k4 = 0; k4 < FIN / 4; ++k4) {
        float4 v = xr[k4];
        #pragma unroll
        for (int kk = 0; kk < 4; ++kk) {
            float vk = (kk == 0) ? v.x : (kk == 1) ? v.y : (kk == 2) ? v.z : v.w;
            float4 w = *(const float4*)&wsm[k4 * 4 + kk][g];
            a0 += vk * w.x;
            a1 += vk * w.y;
            a2 += vk * w.z;
            a3 += vk * w.w;
        }
    }
    float di = dinv[node];
    float4 r = {a0 * di, a1 * di, a2 * di, a3 * di};
    *(float4*)(h1s + (size_t)node * HD + g) = r;
}

// ---- gather layer 1 + epilogue: h2 = relu(dinv*(h1s[i] + sum h1s[csr]) + b1) ----
// 16 lanes per node: lane f reads feature f -> 64B coalesced per edge
__global__ __launch_bounds__(256) void k_gather1(const int* __restrict__ rowptr,
                                                 const int* __restrict__ csr,
                                                 const float* __restrict__ h1s,
                                                 const float* __restrict__ dinv,
                                                 const float* __restrict__ b1,
                                                 float* __restrict__ h2) {
    int node = blockIdx.x * 16 + (threadIdx.x >> 4);
    if (node >= NN) return;
    int f = threadIdx.x & 15;
    float acc = h1s[(size_t)node * HD + f];      // self-loop term
    int e0 = rowptr[node], e1 = rowptr[node + 1];
    for (int e = e0; e < e1; ++e) {
        int s = csr[e];                           // broadcast within 16-lane group
        acc += h1s[(size_t)s * HD + f];
    }
    float v = dinv[node] * acc + b1[f];
    h2[(size_t)node * HD + f] = fmaxf(v, 0.f);
}

// ---- g_s = (h2 @ W2) * dinv : one thread per node ----
__global__ void k_gemm2(const float* __restrict__ h2, const float* __restrict__ W2,
                        const float* __restrict__ dinv, float* __restrict__ g_s) {
    int i = blockIdx.x * 256 + threadIdx.x;
    if (i >= NN) return;
    const float* hr = h2 + (size_t)i * HD;
    float a0 = 0.f, a1 = 0.f;
    #pragma unroll
    for (int k = 0; k < HD; ++k) {
        float h = hr[k];
        a0 += h * W2[k * 2];
        a1 += h * W2[k * 2 + 1];
    }
    float di = dinv[i];
    g_s[(size_t)i * 2]     = a0 * di;
    g_s[(size_t)i * 2 + 1] = a1 * di;
}

// ---- gather layer 2 + log_softmax: one thread per node ----
__global__ void k_gather2(const int* __restrict__ rowptr, const int* __restrict__ csr,
                          const float* __restrict__ g_s, const float* __restrict__ dinv,
                          const float* __restrict__ b2, float* __restrict__ out) {
    int i = blockIdx.x * 256 + threadIdx.x;
    if (i >= NN) return;
    const float2* g2 = (const float2*)g_s;
    float2 acc = g2[i];                           // self-loop term
    int e0 = rowptr[i], e1 = rowptr[i + 1];
    for (int e = e0; e < e1; ++e) {
        float2 v = g2[csr[e]];
        acc.x += v.x;
        acc.y += v.y;
    }
    float di = dinv[i];
    float o0 = acc.x * di + b2[0];
    float o1 = acc.y * di + b2[1];
    float mx = fmaxf(o0, o1);
    float l = mx + logf(__expf(o0 - mx) + __expf(o1 - mx));
    out[(size_t)i * 2]     = o0 - l;
    out[(size_t)i * 2 + 1] = o1 - l;
}

extern "C" void kernel_launch(void* const* d_in, const int* in_sizes, int n_in,
                              void* d_out, int out_size, void* d_ws, size_t ws_size,
                              hipStream_t stream) {
    const float* x   = (const float*)d_in[0];
    const int* ei    = (const int*)d_in[1];
    const int* src   = ei;
    const int* dst   = ei + NE;
    const float* W1  = (const float*)d_in[2];
    const float* b1  = (const float*)d_in[3];
    const float* W2  = (const float*)d_in[4];
    const float* b2  = (const float*)d_in[5];
    float* out = (float*)d_out;

    char* w = (char*)d_ws;
    float* dinv   = (float*)w;                          w += NN * 4;
    int*   cnt    = (int*)w;                            w += NN * 4;
    int*   rowptr = (int*)w;                            w += (NN + 1) * 4;
    int*   next   = (int*)w;                            w += NN * 4;
    int*   csr    = (int*)w;                            w += (size_t)NE * 4;   // 12.8 MB
    float* h1s    = (float*)w;                          w += (size_t)NN * HD * 4;  // 6.4 MB
    float* h2     = (float*)w;                          w += (size_t)NN * HD * 4;  // 6.4 MB
    float* g_s    = (float*)w;                          w += NN * CD * 4;
    // total ~28 MB

    k_zero<<<(NN + 255) / 256, 256, 0, stream>>>(cnt);
    k_hist<<<(NE + 255) / 256, 256, 0, stream>>>(dst, cnt);
    k_scan<<<1, 1024, 0, stream>>>(cnt, rowptr, next, dinv);
    k_fill<<<(NE + 255) / 256, 256, 0, stream>>>(src, dst, next, csr);
    k_gemm1<<<(NN * 4 + 255) / 256, 256, 0, stream>>>(x, W1, dinv, h1s);
    k_gather1<<<(NN + 15) / 16, 256, 0, stream>>>(rowptr, csr, h1s, dinv, b1, h2);
    k_gemm2<<<(NN + 255) / 256, 256, 0, stream>>>(h2, W2, dinv, g_s);
    k_gather2<<<(NN + 255) / 256, 256, 0, stream>>>(rowptr, csr, g_s, dinv, b2, out);
}

// Round 4
// 648.462 us; speedup vs baseline: 1.9101x; 1.4276x over previous
//
#include <hip/hip_runtime.h>
#include <hip/hip_bf16.h>

#define NN 100000
#define NE 3200000
#define FIN 128
#define HD 16
#define CD 2
#define NB 98            // ceil(NN / 1024)

// ---- zero the degree histogram ----
__global__ void k_zero(int* __restrict__ cnt) {
    int i = blockIdx.x * 256 + threadIdx.x;
    if (i < NN) cnt[i] = 0;
}

// ---- histogram of dst (in-degree, excluding self-loop) ----
__global__ void k_hist(const int* __restrict__ dst, int* __restrict__ cnt) {
    int e = blockIdx.x * 256 + threadIdx.x;
    if (e < NE) atomicAdd(&cnt[dst[e]], 1);
}

// ---- scan phase 1: per-block (1024-elem slab) sum ----
__global__ __launch_bounds__(256) void k_reduce(const int* __restrict__ cnt,
                                                int* __restrict__ bsum) {
    __shared__ int sm[256];
    int b = blockIdx.x, t = threadIdx.x;
    int base = b * 1024;
    int s = 0;
    #pragma unroll
    for (int j = 0; j < 4; ++j) {
        int i = base + j * 256 + t;
        if (i < NN) s += cnt[i];
    }
    sm[t] = s;
    __syncthreads();
    for (int off = 128; off > 0; off >>= 1) {
        if (t < off) sm[t] += sm[t + off];
        __syncthreads();
    }
    if (t == 0) bsum[b] = sm[0];
}

// ---- scan phase 2: scan the 98 block sums (1 tiny block) ----
__global__ void k_scanp(const int* __restrict__ bsum, int* __restrict__ boff,
                        int* __restrict__ rowptr) {
    __shared__ int sm[128];
    int t = threadIdx.x;
    sm[t] = (t < NB) ? bsum[t] : 0;
    __syncthreads();
    for (int off = 1; off < 128; off <<= 1) {
        int v = 0;
        if (t >= off) v = sm[t - off];
        __syncthreads();
        if (t >= off) sm[t] += v;
        __syncthreads();
    }
    if (t < NB) boff[t] = (t == 0) ? 0 : sm[t - 1];
    if (t == 127) rowptr[NN] = sm[NB - 1];   // = NE
}

// ---- scan phase 3: local exclusive scan + boff, emit rowptr/next/dinv ----
__global__ __launch_bounds__(256) void k_apply(const int* __restrict__ cnt,
                                               const int* __restrict__ boff,
                                               int* __restrict__ rowptr,
                                               int* __restrict__ next,
                                               float* __restrict__ dinv) {
    __shared__ int sm[256];
    int b = blockIdx.x, t = threadIdx.x;
    int base = b * 1024 + t * 4;
    int c[4];
    #pragma unroll
    for (int j = 0; j < 4; ++j) {
        int i = base + j;
        c[j] = (i < NN) ? cnt[i] : 0;
    }
    sm[t] = c[0] + c[1] + c[2] + c[3];
    __syncthreads();
    for (int off = 1; off < 256; off <<= 1) {
        int v = 0;
        if (t >= off) v = sm[t - off];
        __syncthreads();
        if (t >= off) sm[t] += v;
        __syncthreads();
    }
    int excl = boff[b] + ((t == 0) ? 0 : sm[t - 1]);
    #pragma unroll
    for (int j = 0; j < 4; ++j) {
        int i = base + j;
        if (i < NN) {
            rowptr[i] = excl;
            next[i] = excl;
            dinv[i] = rsqrtf((float)c[j] + 1.0f);
            excl += c[j];
        }
    }
}

// ---- CSR fill: csr[pos] = src, pos via int atomic on next[] ----
__global__ void k_fill(const int* __restrict__ src, const int* __restrict__ dst,
                       int* __restrict__ next, int* __restrict__ csr) {
    int e = blockIdx.x * 256 + threadIdx.x;
    if (e >= NE) return;
    int d = dst[e];
    int pos = atomicAdd(&next[d], 1);
    csr[pos] = src[e];
}

// ---- h1s = (x @ W1) * dinv[node] : 4 threads/node, 4 outputs each ----
__global__ __launch_bounds__(256) void k_gemm1(const float* __restrict__ x,
                                               const float* __restrict__ W1,
                                               const float* __restrict__ dinv,
                                               float* __restrict__ h1s) {
    __shared__ float wsm[FIN][HD];   // 8 KB
    for (int i = threadIdx.x; i < FIN * HD; i += 256) wsm[i >> 4][i & 15] = W1[i];
    __syncthreads();
    int t = blockIdx.x * 256 + threadIdx.x;
    int node = t >> 2;
    if (node >= NN) return;
    int g = (t & 3) * 4;
    const float4* xr = (const float4*)(x + (size_t)node * FIN);
    float a0 = 0.f, a1 = 0.f, a2 = 0.f, a3 = 0.f;
    #pragma unroll
    for (int k4 = 0; k4 < FIN / 4; ++k4) {
        float4 v = xr[k4];
        #pragma unroll
        for (int kk = 0; kk < 4; ++kk) {
            float vk = (kk == 0) ? v.x : (kk == 1) ? v.y : (kk == 2) ? v.z : v.w;
            float4 w = *(const float4*)&wsm[k4 * 4 + kk][g];
            a0 += vk * w.x;
            a1 += vk * w.y;
            a2 += vk * w.z;
            a3 += vk * w.w;
        }
    }
    float di = dinv[node];
    float4 r = {a0 * di, a1 * di, a2 * di, a3 * di};
    *(float4*)(h1s + (size_t)node * HD + g) = r;
}

// ---- gather layer 1 + epilogue: h2 = relu(dinv*(h1s[i] + sum h1s[csr]) + b1) ----
__global__ __launch_bounds__(256) void k_gather1(const int* __restrict__ rowptr,
                                                 const int* __restrict__ csr,
                                                 const float* __restrict__ h1s,
                                                 const float* __restrict__ dinv,
                                                 const float* __restrict__ b1,
                                                 float* __restrict__ h2) {
    int node = blockIdx.x * 16 + (threadIdx.x >> 4);
    if (node >= NN) return;
    int f = threadIdx.x & 15;
    float acc = h1s[(size_t)node * HD + f];      // self-loop term
    int e0 = rowptr[node], e1 = rowptr[node + 1];
    for (int e = e0; e < e1; ++e) {
        int s = csr[e];                           // broadcast within 16-lane group
        acc += h1s[(size_t)s * HD + f];
    }
    float v = dinv[node] * acc + b1[f];
    h2[(size_t)node * HD + f] = fmaxf(v, 0.f);
}

// ---- g_s = (h2 @ W2) * dinv : one thread per node ----
__global__ void k_gemm2(const float* __restrict__ h2, const float* __restrict__ W2,
                        const float* __restrict__ dinv, float* __restrict__ g_s) {
    int i = blockIdx.x * 256 + threadIdx.x;
    if (i >= NN) return;
    const float* hr = h2 + (size_t)i * HD;
    float a0 = 0.f, a1 = 0.f;
    #pragma unroll
    for (int k = 0; k < HD; ++k) {
        float h = hr[k];
        a0 += h * W2[k * 2];
        a1 += h * W2[k * 2 + 1];
    }
    float di = dinv[i];
    g_s[(size_t)i * 2]     = a0 * di;
    g_s[(size_t)i * 2 + 1] = a1 * di;
}

// ---- gather layer 2 + log_softmax: one thread per node ----
__global__ void k_gather2(const int* __restrict__ rowptr, const int* __restrict__ csr,
                          const float* __restrict__ g_s, const float* __restrict__ dinv,
                          const float* __restrict__ b2, float* __restrict__ out) {
    int i = blockIdx.x * 256 + threadIdx.x;
    if (i >= NN) return;
    const float2* g2 = (const float2*)g_s;
    float2 acc = g2[i];                           // self-loop term
    int e0 = rowptr[i], e1 = rowptr[i + 1];
    for (int e = e0; e < e1; ++e) {
        float2 v = g2[csr[e]];
        acc.x += v.x;
        acc.y += v.y;
    }
    float di = dinv[i];
    float o0 = acc.x * di + b2[0];
    float o1 = acc.y * di + b2[1];
    float mx = fmaxf(o0, o1);
    float l = mx + logf(__expf(o0 - mx) + __expf(o1 - mx));
    out[(size_t)i * 2]     = o0 - l;
    out[(size_t)i * 2 + 1] = o1 - l;
}

extern "C" void kernel_launch(void* const* d_in, const int* in_sizes, int n_in,
                              void* d_out, int out_size, void* d_ws, size_t ws_size,
                              hipStream_t stream) {
    const float* x   = (const float*)d_in[0];
    const int* ei    = (const int*)d_in[1];
    const int* src   = ei;
    const int* dst   = ei + NE;
    const float* W1  = (const float*)d_in[2];
    const float* b1  = (const float*)d_in[3];
    const float* W2  = (const float*)d_in[4];
    const float* b2  = (const float*)d_in[5];
    float* out = (float*)d_out;

    char* w = (char*)d_ws;
    float* dinv   = (float*)w;                          w += NN * 4;
    int*   cnt    = (int*)w;                            w += NN * 4;
    int*   rowptr = (int*)w;                            w += (NN + 1) * 4;
    int*   next   = (int*)w;                            w += NN * 4;
    int*   bsum   = (int*)w;                            w += 128 * 4;
    int*   boff   = (int*)w;                            w += 128 * 4;
    int*   csr    = (int*)w;                            w += (size_t)NE * 4;       // 12.8 MB
    float* h1s    = (float*)w;                          w += (size_t)NN * HD * 4;  // 6.4 MB
    float* h2     = (float*)w;                          w += (size_t)NN * HD * 4;  // 6.4 MB
    float* g_s    = (float*)w;                          w += NN * CD * 4;

    k_zero<<<(NN + 255) / 256, 256, 0, stream>>>(cnt);
    k_hist<<<(NE + 255) / 256, 256, 0, stream>>>(dst, cnt);
    k_reduce<<<NB, 256, 0, stream>>>(cnt, bsum);
    k_scanp<<<1, 128, 0, stream>>>(bsum, boff, rowptr);
    k_apply<<<NB, 256, 0, stream>>>(cnt, boff, rowptr, next, dinv);
    k_fill<<<(NE + 255) / 256, 256, 0, stream>>>(src, dst, next, csr);
    k_gemm1<<<(NN * 4 + 255) / 256, 256, 0, stream>>>(x, W1, dinv, h1s);
    k_gather1<<<(NN + 15) / 16, 256, 0, stream>>>(rowptr, csr, h1s, dinv, b1, h2);
    k_gemm2<<<(NN + 255) / 256, 256, 0, stream>>>(h2, W2, dinv, g_s);
    k_gather2<<<(NN + 255) / 256, 256, 0, stream>>>(rowptr, csr, g_s, dinv, b2, out);
}

// Round 5
// 576.074 us; speedup vs baseline: 2.1501x; 1.1257x over previous
//
#include <hip/hip_runtime.h>
#include <hip/hip_bf16.h>

#define NN 100000
#define NE 3200000
#define FIN 128
#define HD 16
#define CD 2

#define BSH 7                        // bucket shift
#define BSPAN 128                    // nodes per bucket
#define NBKT 782                     // ceil(NN / BSPAN)
#define CHUNK 8192                   // edges per partition block
#define NPB ((NE + CHUNK - 1) / CHUNK)   // 391

// ---- zero bucket counts ----
__global__ void k_zb(int* __restrict__ bcnt) {
    int i = blockIdx.x * 256 + threadIdx.x;
    if (i < NBKT) bcnt[i] = 0;
}

// ---- bucket histogram: LDS-privatized, then one global add per bucket ----
__global__ __launch_bounds__(256) void k_bhist(const int* __restrict__ dst,
                                               int* __restrict__ bcnt) {
    __shared__ int h[NBKT];
    for (int i = threadIdx.x; i < NBKT; i += 256) h[i] = 0;
    __syncthreads();
    int base = blockIdx.x * CHUNK;
    #pragma unroll
    for (int j = 0; j < CHUNK / 256; ++j) {
        int e = base + j * 256 + threadIdx.x;
        if (e < NE) atomicAdd(&h[dst[e] >> BSH], 1);
    }
    __syncthreads();
    for (int i = threadIdx.x; i < NBKT; i += 256) {
        int v = h[i];
        if (v) atomicAdd(&bcnt[i], v);
    }
}

// ---- scan 782 bucket counts -> boff (exclusive), bcur copy ----
__global__ __launch_bounds__(1024) void k_scanb(const int* __restrict__ bcnt,
                                                int* __restrict__ boff,
                                                int* __restrict__ bcur) {
    __shared__ int sm[1024];
    int t = threadIdx.x;
    sm[t] = (t < NBKT) ? bcnt[t] : 0;
    __syncthreads();
    for (int off = 1; off < 1024; off <<= 1) {
        int v = 0;
        if (t >= off) v = sm[t - off];
        __syncthreads();
        if (t >= off) sm[t] += v;
        __syncthreads();
    }
    if (t < NBKT) {
        int ex = t ? sm[t - 1] : 0;
        boff[t] = ex;
        bcur[t] = ex;
    }
    if (t == 1023) boff[NBKT] = sm[1023];   // = NE
}

// ---- partition: write packed (src | dlocal<<17), grouped by bucket ----
__global__ __launch_bounds__(256) void k_part(const int* __restrict__ src,
                                              const int* __restrict__ dst,
                                              int* __restrict__ bcur,
                                              unsigned int* __restrict__ csr) {
    __shared__ int h[NBKT];
    __shared__ int base[NBKT];
    for (int i = threadIdx.x; i < NBKT; i += 256) h[i] = 0;
    __syncthreads();
    int cb = blockIdx.x * CHUNK;
    #pragma unroll
    for (int j = 0; j < CHUNK / 256; ++j) {
        int e = cb + j * 256 + threadIdx.x;
        if (e < NE) atomicAdd(&h[dst[e] >> BSH], 1);
    }
    __syncthreads();
    for (int i = threadIdx.x; i < NBKT; i += 256) {
        int v = h[i];
        base[i] = v ? atomicAdd(&bcur[i], v) : 0;
    }
    __syncthreads();
    for (int i = threadIdx.x; i < NBKT; i += 256) h[i] = 0;   // reuse as local cursor
    __syncthreads();
    #pragma unroll
    for (int j = 0; j < CHUNK / 256; ++j) {
        int e = cb + j * 256 + threadIdx.x;
        if (e < NE) {
            int d = dst[e];
            int b = d >> BSH;
            int pos = atomicAdd(&h[b], 1);
            csr[base[b] + pos] = (unsigned)src[e] | ((unsigned)(d & (BSPAN - 1)) << 17);
        }
    }
}

// ---- per-bucket degree -> dinv ----
__global__ __launch_bounds__(256) void k_degb(const int* __restrict__ boff,
                                              const unsigned int* __restrict__ csr,
                                              float* __restrict__ dinv) {
    __shared__ int cnt[BSPAN];
    int b = blockIdx.x, t = threadIdx.x;
    if (t < BSPAN) cnt[t] = 0;
    __syncthreads();
    int e0 = boff[b], e1 = boff[b + 1];
    for (int e = e0 + t; e < e1; e += 256) atomicAdd(&cnt[csr[e] >> 17], 1);
    __syncthreads();
    int node = b * BSPAN + t;
    if (t < BSPAN && node < NN) dinv[node] = rsqrtf((float)cnt[t] + 1.0f);
}

// ---- h1s = (x @ W1) * dinv[node] : 4 threads/node, 4 outputs each ----
__global__ __launch_bounds__(256) void k_gemm1(const float* __restrict__ x,
                                               const float* __restrict__ W1,
                                               const float* __restrict__ dinv,
                                               float* __restrict__ h1s) {
    __shared__ float wsm[FIN][HD];   // 8 KB
    for (int i = threadIdx.x; i < FIN * HD; i += 256) wsm[i >> 4][i & 15] = W1[i];
    __syncthreads();
    int t = blockIdx.x * 256 + threadIdx.x;
    int node = t >> 2;
    if (node >= NN) return;
    int g = (t & 3) * 4;
    const float4* xr = (const float4*)(x + (size_t)node * FIN);
    float a0 = 0.f, a1 = 0.f, a2 = 0.f, a3 = 0.f;
    #pragma unroll
    for (int k4 = 0; k4 < FIN / 4; ++k4) {
        float4 v = xr[k4];
        #pragma unroll
        for (int kk = 0; kk < 4; ++kk) {
            float vk = (kk == 0) ? v.x : (kk == 1) ? v.y : (kk == 2) ? v.z : v.w;
            float4 w = *(const float4*)&wsm[k4 * 4 + kk][g];
            a0 += vk * w.x;
            a1 += vk * w.y;
            a2 += vk * w.z;
            a3 += vk * w.w;
        }
    }
    float di = dinv[node];
    float4 r = {a0 * di, a1 * di, a2 * di, a3 * di};
    *(float4*)(h1s + (size_t)node * HD + g) = r;
}

// ---- layer-1 aggregate per bucket: LDS f32 atomics, fused ReLU epilogue ----
__global__ __launch_bounds__(256) void k_agg1(const int* __restrict__ boff,
                                              const unsigned int* __restrict__ csr,
                                              const float* __restrict__ h1s,
                                              const float* __restrict__ dinv,
                                              const float* __restrict__ b1,
                                              float* __restrict__ h2) {
    __shared__ float acc[BSPAN * HD];   // 8 KB
    int b = blockIdx.x, t = threadIdx.x;
    for (int i = t; i < BSPAN * HD; i += 256) acc[i] = 0.f;
    __syncthreads();
    int f = t & 15, grp = t >> 4;        // 16 edge-groups of 16 lanes
    int e0 = boff[b], e1 = boff[b + 1];
    for (int e = e0 + grp; e < e1; e += 16) {
        unsigned p = csr[e];
        int s = p & 0x1FFFF;
        int dl = p >> 17;
        atomicAdd(&acc[dl * HD + f], h1s[(size_t)s * HD + f]);
    }
    __syncthreads();
    for (int i = t; i < BSPAN * HD; i += 256) {
        int node = b * BSPAN + (i >> 4);
        if (node < NN) {
            int ff = i & 15;
            float v = dinv[node] * (acc[i] + h1s[(size_t)node * HD + ff]) + b1[ff];
            h2[(size_t)node * HD + ff] = fmaxf(v, 0.f);
        }
    }
}

// ---- g_s = (h2 @ W2) * dinv : one thread per node ----
__global__ void k_gemm2(const float* __restrict__ h2, const float* __restrict__ W2,
                        const float* __restrict__ dinv, float* __restrict__ g_s) {
    int i = blockIdx.x * 256 + threadIdx.x;
    if (i >= NN) return;
    const float* hr = h2 + (size_t)i * HD;
    float a0 = 0.f, a1 = 0.f;
    #pragma unroll
    for (int k = 0; k < HD; ++k) {
        float h = hr[k];
        a0 += h * W2[k * 2];
        a1 += h * W2[k * 2 + 1];
    }
    float di = dinv[i];
    g_s[(size_t)i * 2]     = a0 * di;
    g_s[(size_t)i * 2 + 1] = a1 * di;
}

// ---- layer-2 aggregate per bucket + log_softmax ----
__global__ __launch_bounds__(256) void k_agg2(const int* __restrict__ boff,
                                              const unsigned int* __restrict__ csr,
                                              const float* __restrict__ g_s,
                                              const float* __restrict__ dinv,
                                              const float* __restrict__ b2,
                                              float* __restrict__ out) {
    __shared__ float acc[BSPAN * 2];
    int b = blockIdx.x, t = threadIdx.x;
    for (int i = t; i < BSPAN * 2; i += 256) acc[i] = 0.f;
    __syncthreads();
    int f = t & 1, grp = t >> 1;         // 128 edge-groups of 2 lanes
    int e0 = boff[b], e1 = boff[b + 1];
    for (int e = e0 + grp; e < e1; e += 128) {
        unsigned p = csr[e];
        int s = p & 0x1FFFF;
        int dl = p >> 17;
        atomicAdd(&acc[dl * 2 + f], g_s[(size_t)s * 2 + f]);
    }
    __syncthreads();
    int node = b * BSPAN + t;
    if (t < BSPAN && node < NN) {
        float di = dinv[node];
        float o0 = di * (acc[t * 2]     + g_s[(size_t)node * 2])     + b2[0];
        float o1 = di * (acc[t * 2 + 1] + g_s[(size_t)node * 2 + 1]) + b2[1];
        float mx = fmaxf(o0, o1);
        float l = mx + logf(__expf(o0 - mx) + __expf(o1 - mx));
        out[(size_t)node * 2]     = o0 - l;
        out[(size_t)node * 2 + 1] = o1 - l;
    }
}

extern "C" void kernel_launch(void* const* d_in, const int* in_sizes, int n_in,
                              void* d_out, int out_size, void* d_ws, size_t ws_size,
                              hipStream_t stream) {
    const float* x   = (const float*)d_in[0];
    const int* ei    = (const int*)d_in[1];
    const int* src   = ei;
    const int* dst   = ei + NE;
    const float* W1  = (const float*)d_in[2];
    const float* b1  = (const float*)d_in[3];
    const float* W2  = (const float*)d_in[4];
    const float* b2  = (const float*)d_in[5];
    float* out = (float*)d_out;

    char* w = (char*)d_ws;
    float* dinv        = (float*)w;          w += NN * 4;
    int*   bcnt        = (int*)w;            w += NBKT * 4;
    int*   boff        = (int*)w;            w += (NBKT + 1) * 4;
    int*   bcur        = (int*)w;            w += NBKT * 4;
    unsigned int* csr  = (unsigned int*)w;   w += (size_t)NE * 4;       // 12.8 MB
    float* h1s         = (float*)w;          w += (size_t)NN * HD * 4;  // 6.4 MB
    float* h2          = (float*)w;          w += (size_t)NN * HD * 4;  // 6.4 MB
    float* g_s         = (float*)w;          w += NN * CD * 4;

    k_zb   <<<(NBKT + 255) / 256, 256, 0, stream>>>(bcnt);
    k_bhist<<<NPB, 256, 0, stream>>>(dst, bcnt);
    k_scanb<<<1, 1024, 0, stream>>>(bcnt, boff, bcur);
    k_part <<<NPB, 256, 0, stream>>>(src, dst, bcur, csr);
    k_degb <<<NBKT, 256, 0, stream>>>(boff, csr, dinv);
    k_gemm1<<<(NN * 4 + 255) / 256, 256, 0, stream>>>(x, W1, dinv, h1s);
    k_agg1 <<<NBKT, 256, 0, stream>>>(boff, csr, h1s, dinv, b1, h2);
    k_gemm2<<<(NN + 255) / 256, 256, 0, stream>>>(h2, W2, dinv, g_s);
    k_agg2 <<<NBKT, 256, 0, stream>>>(boff, csr, g_s, dinv, b2, out);
}

// Round 6
// 294.325 us; speedup vs baseline: 4.2084x; 1.9573x over previous
//
#include <hip/hip_runtime.h>
#include <hip/hip_bf16.h>

#define NN 100000
#define NE 3200000
#define FIN 128
#define HD 16
#define CD 2

#define BSH 7                        // bucket shift
#define BSPAN 128                    // nodes per bucket
#define NBKT 782                     // ceil(NN / BSPAN)
#define CHUNK 8192                   // edges per partition block
#define NPB ((NE + CHUNK - 1) / CHUNK)   // 391

__device__ __forceinline__ float bf2f(ushort u) {
    union { float f; unsigned int i; } v; v.i = ((unsigned int)u) << 16; return v.f;
}
__device__ __forceinline__ ushort f2b(float f) {
    union { float f; unsigned int u; } v; v.f = f;
    unsigned int r = (v.u + 0x7FFFu + ((v.u >> 16) & 1u)) >> 16;   // RNE
    return (ushort)r;
}

// ---- zero bucket counts ----
__global__ void k_zb(int* __restrict__ bcnt) {
    int i = blockIdx.x * 256 + threadIdx.x;
    if (i < NBKT) bcnt[i] = 0;
}

// ---- bucket histogram: LDS-privatized ----
__global__ __launch_bounds__(256) void k_bhist(const int* __restrict__ dst,
                                               int* __restrict__ bcnt) {
    __shared__ int h[NBKT];
    for (int i = threadIdx.x; i < NBKT; i += 256) h[i] = 0;
    __syncthreads();
    int base = blockIdx.x * CHUNK;
    #pragma unroll
    for (int j = 0; j < CHUNK / 256; ++j) {
        int e = base + j * 256 + threadIdx.x;
        if (e < NE) atomicAdd(&h[dst[e] >> BSH], 1);
    }
    __syncthreads();
    for (int i = threadIdx.x; i < NBKT; i += 256) {
        int v = h[i];
        if (v) atomicAdd(&bcnt[i], v);
    }
}

// ---- scan 782 bucket counts -> boff (exclusive), bcur copy ----
__global__ __launch_bounds__(1024) void k_scanb(const int* __restrict__ bcnt,
                                                int* __restrict__ boff,
                                                int* __restrict__ bcur) {
    __shared__ int sm[1024];
    int t = threadIdx.x;
    sm[t] = (t < NBKT) ? bcnt[t] : 0;
    __syncthreads();
    for (int off = 1; off < 1024; off <<= 1) {
        int v = 0;
        if (t >= off) v = sm[t - off];
        __syncthreads();
        if (t >= off) sm[t] += v;
        __syncthreads();
    }
    if (t < NBKT) {
        int ex = t ? sm[t - 1] : 0;
        boff[t] = ex;
        bcur[t] = ex;
    }
    if (t == 1023) boff[NBKT] = sm[1023];   // = NE
}

// ---- partition: write packed (src | dlocal<<17), grouped by bucket ----
__global__ __launch_bounds__(256) void k_part(const int* __restrict__ src,
                                              const int* __restrict__ dst,
                                              int* __restrict__ bcur,
                                              unsigned int* __restrict__ csrb) {
    __shared__ int h[NBKT];
    __shared__ int base[NBKT];
    for (int i = threadIdx.x; i < NBKT; i += 256) h[i] = 0;
    __syncthreads();
    int cb = blockIdx.x * CHUNK;
    #pragma unroll
    for (int j = 0; j < CHUNK / 256; ++j) {
        int e = cb + j * 256 + threadIdx.x;
        if (e < NE) atomicAdd(&h[dst[e] >> BSH], 1);
    }
    __syncthreads();
    for (int i = threadIdx.x; i < NBKT; i += 256) {
        int v = h[i];
        base[i] = v ? atomicAdd(&bcur[i], v) : 0;
    }
    __syncthreads();
    for (int i = threadIdx.x; i < NBKT; i += 256) h[i] = 0;   // reuse as local cursor
    __syncthreads();
    #pragma unroll
    for (int j = 0; j < CHUNK / 256; ++j) {
        int e = cb + j * 256 + threadIdx.x;
        if (e < NE) {
            int d = dst[e];
            int b = d >> BSH;
            int pos = atomicAdd(&h[b], 1);
            csrb[base[b] + pos] = (unsigned)src[e] | ((unsigned)(d & (BSPAN - 1)) << 17);
        }
    }
}

// ---- per-bucket counting sort: csrb -> csr2 (per-node order), rowptr, dinv ----
__global__ __launch_bounds__(256) void k_sortb(const int* __restrict__ boff,
                                               const unsigned int* __restrict__ csrb,
                                               int* __restrict__ csr2,
                                               int* __restrict__ rowptr,
                                               float* __restrict__ dinv) {
    __shared__ int cnt[BSPAN];
    __shared__ int sc[BSPAN];
    __shared__ int cur[BSPAN];
    int b = blockIdx.x, t = threadIdx.x;
    if (t < BSPAN) cnt[t] = 0;
    __syncthreads();
    int e0 = boff[b], e1 = boff[b + 1];
    for (int e = e0 + t; e < e1; e += 256) atomicAdd(&cnt[csrb[e] >> 17], 1);
    __syncthreads();
    if (t < BSPAN) sc[t] = cnt[t];
    __syncthreads();
    for (int off = 1; off < BSPAN; off <<= 1) {
        int v = 0;
        if (t < BSPAN && t >= off) v = sc[t - off];
        __syncthreads();
        if (t < BSPAN && t >= off) sc[t] += v;
        __syncthreads();
    }
    if (t < BSPAN) {
        int ex = e0 + (t ? sc[t - 1] : 0);
        cur[t] = ex;
        int node = b * BSPAN + t;
        if (node < NN) {
            rowptr[node] = ex;
            dinv[node] = rsqrtf((float)cnt[t] + 1.0f);
        }
    }
    if (b == 0 && t == 0) rowptr[NN] = boff[NBKT];   // = NE
    __syncthreads();
    for (int e = e0 + t; e < e1; e += 256) {
        unsigned p = csrb[e];
        int pos = atomicAdd(&cur[p >> 17], 1);
        csr2[pos] = (int)(p & 0x1FFFF);
    }
}

// ---- h1b = bf16((x @ W1) * dinv[node]) : 4 threads/node, 4 outputs each ----
__global__ __launch_bounds__(256) void k_gemm1(const float* __restrict__ x,
                                               const float* __restrict__ W1,
                                               const float* __restrict__ dinv,
                                               ushort* __restrict__ h1b) {
    __shared__ float wsm[FIN][HD];   // 8 KB
    for (int i = threadIdx.x; i < FIN * HD; i += 256) wsm[i >> 4][i & 15] = W1[i];
    __syncthreads();
    int t = blockIdx.x * 256 + threadIdx.x;
    int node = t >> 2;
    if (node >= NN) return;
    int g = (t & 3) * 4;
    const float4* xr = (const float4*)(x + (size_t)node * FIN);
    float a0 = 0.f, a1 = 0.f, a2 = 0.f, a3 = 0.f;
    #pragma unroll
    for (int k4 = 0; k4 < FIN / 4; ++k4) {
        float4 v = xr[k4];
        #pragma unroll
        for (int kk = 0; kk < 4; ++kk) {
            float vk = (kk == 0) ? v.x : (kk == 1) ? v.y : (kk == 2) ? v.z : v.w;
            float4 w = *(const float4*)&wsm[k4 * 4 + kk][g];
            a0 += vk * w.x;
            a1 += vk * w.y;
            a2 += vk * w.z;
            a3 += vk * w.w;
        }
    }
    float di = dinv[node];
    ushort4 r = {f2b(a0 * di), f2b(a1 * di), f2b(a2 * di), f2b(a3 * di)};
    *(ushort4*)(h1b + (size_t)node * HD + g) = r;
}

// ---- layer-1 aggregate: one wave per node, 4 edge-slots x 16 features ----
__global__ __launch_bounds__(256) void k_agg1(const int* __restrict__ rowptr,
                                              const int* __restrict__ csr2,
                                              const ushort* __restrict__ h1b,
                                              const float* __restrict__ dinv,
                                              const float* __restrict__ b1,
                                              float* __restrict__ h2) {
    int wid = (blockIdx.x * 256 + threadIdx.x) >> 6;
    if (wid >= NN) return;
    int lane = threadIdx.x & 63;
    int slot = lane >> 4, f = lane & 15;
    int e0 = rowptr[wid], e1 = rowptr[wid + 1];
    float acc = 0.f, acc2 = 0.f;
    int e = e0 + slot;
    for (; e + 4 < e1; e += 8) {                 // 2 independent chains
        int s0 = csr2[e];
        int s1 = csr2[e + 4];
        acc  += bf2f(h1b[(size_t)s0 * HD + f]);
        acc2 += bf2f(h1b[(size_t)s1 * HD + f]);
    }
    if (e < e1) acc += bf2f(h1b[(size_t)csr2[e] * HD + f]);
    acc += acc2;
    acc += __shfl_xor(acc, 16, 64);
    acc += __shfl_xor(acc, 32, 64);
    if (slot == 0) {
        float v = dinv[wid] * (acc + bf2f(h1b[(size_t)wid * HD + f])) + b1[f];
        h2[(size_t)wid * HD + f] = fmaxf(v, 0.f);
    }
}

// ---- g_s = (h2 @ W2) * dinv : one thread per node ----
__global__ void k_gemm2(const float* __restrict__ h2, const float* __restrict__ W2,
                        const float* __restrict__ dinv, float* __restrict__ g_s) {
    int i = blockIdx.x * 256 + threadIdx.x;
    if (i >= NN) return;
    const float* hr = h2 + (size_t)i * HD;
    float a0 = 0.f, a1 = 0.f;
    #pragma unroll
    for (int k = 0; k < HD; ++k) {
        float h = hr[k];
        a0 += h * W2[k * 2];
        a1 += h * W2[k * 2 + 1];
    }
    float di = dinv[i];
    g_s[(size_t)i * 2]     = a0 * di;
    g_s[(size_t)i * 2 + 1] = a1 * di;
}

// ---- layer-2 aggregate: one wave per node, 32 slots x 2 feats, fused softmax ----
__global__ __launch_bounds__(256) void k_agg2(const int* __restrict__ rowptr,
                                              const int* __restrict__ csr2,
                                              const float* __restrict__ g_s,
                                              const float* __restrict__ dinv,
                                              const float* __restrict__ b2,
                                              float* __restrict__ out) {
    int wid = (blockIdx.x * 256 + threadIdx.x) >> 6;
    if (wid >= NN) return;
    int lane = threadIdx.x & 63;
    int slot = lane >> 1, f = lane & 1;
    int e0 = rowptr[wid], e1 = rowptr[wid + 1];
    float acc = 0.f;
    for (int e = e0 + slot; e < e1; e += 32)
        acc += g_s[(size_t)csr2[e] * 2 + f];
    #pragma unroll
    for (int m = 2; m <= 32; m <<= 1) acc += __shfl_xor(acc, m, 64);
    if (slot == 0) {
        float di = dinv[wid];
        float o = di * (acc + g_s[(size_t)wid * 2 + f]) + b2[f];
        float other = __shfl_xor(o, 1, 64);
        float mx = fmaxf(o, other);
        float l = mx + logf(__expf(o - mx) + __expf(other - mx));
        out[(size_t)wid * 2 + f] = o - l;
    }
}

extern "C" void kernel_launch(void* const* d_in, const int* in_sizes, int n_in,
                              void* d_out, int out_size, void* d_ws, size_t ws_size,
                              hipStream_t stream) {
    const float* x   = (const float*)d_in[0];
    const int* ei    = (const int*)d_in[1];
    const int* src   = ei;
    const int* dst   = ei + NE;
    const float* W1  = (const float*)d_in[2];
    const float* b1  = (const float*)d_in[3];
    const float* W2  = (const float*)d_in[4];
    const float* b2  = (const float*)d_in[5];
    float* out = (float*)d_out;

    char* w = (char*)d_ws;
    float* dinv        = (float*)w;          w += NN * 4;
    int*   bcnt        = (int*)w;            w += NBKT * 4;
    int*   boff        = (int*)w;            w += (NBKT + 1) * 4;
    int*   bcur        = (int*)w;            w += NBKT * 4;
    int*   rowptr      = (int*)w;            w += (NN + 1) * 4;
    unsigned int* csrb = (unsigned int*)w;   w += (size_t)NE * 4;       // 12.8 MB
    int*   csr2        = (int*)w;            w += (size_t)NE * 4;       // 12.8 MB
    ushort* h1b        = (ushort*)w;         w += (size_t)NN * HD * 2;  // 3.2 MB
    float* h2          = (float*)w;          w += (size_t)NN * HD * 4;  // 6.4 MB
    float* g_s         = (float*)w;          w += NN * CD * 4;

    k_zb   <<<(NBKT + 255) / 256, 256, 0, stream>>>(bcnt);
    k_bhist<<<NPB, 256, 0, stream>>>(dst, bcnt);
    k_scanb<<<1, 1024, 0, stream>>>(bcnt, boff, bcur);
    k_part <<<NPB, 256, 0, stream>>>(src, dst, bcur, csrb);
    k_sortb<<<NBKT, 256, 0, stream>>>(boff, csrb, csr2, rowptr, dinv);
    k_gemm1<<<(NN * 4 + 255) / 256, 256, 0, stream>>>(x, W1, dinv, h1b);
    k_agg1 <<<(NN * 64 + 255) / 256, 256, 0, stream>>>(rowptr, csr2, h1b, dinv, b1, h2);
    k_gemm2<<<(NN + 255) / 256, 256, 0, stream>>>(h2, W2, dinv, g_s);
    k_agg2 <<<(NN * 64 + 255) / 256, 256, 0, stream>>>(rowptr, csr2, g_s, dinv, b2, out);
}

// Round 7
// 281.172 us; speedup vs baseline: 4.4053x; 1.0468x over previous
//
#include <hip/hip_runtime.h>
#include <hip/hip_bf16.h>

#define NN 100000
#define NE 3200000
#define FIN 128
#define HD 16
#define CD 2

#define BSH 7                        // bucket shift
#define BSPAN 128                    // nodes per bucket
#define NBKT 782                     // ceil(NN / BSPAN)
#define CHUNK 4096                   // edges per partition block
#define NPB ((NE + CHUNK - 1) / CHUNK)   // 782

__device__ __forceinline__ float bf2f(ushort u) {
    union { float f; unsigned int i; } v; v.i = ((unsigned int)u) << 16; return v.f;
}
__device__ __forceinline__ ushort f2b(float f) {
    union { float f; unsigned int u; } v; v.f = f;
    unsigned int r = (v.u + 0x7FFFu + ((v.u >> 16) & 1u)) >> 16;   // RNE
    return (ushort)r;
}

// ---- pass 1: per-block bucket counts -> cntmat[b][bucket] (coalesced rows) ----
__global__ __launch_bounds__(256) void k_cnt(const int* __restrict__ dst,
                                             int* __restrict__ cntmat) {
    __shared__ int h[NBKT];
    for (int i = threadIdx.x; i < NBKT; i += 256) h[i] = 0;
    __syncthreads();
    int cb = blockIdx.x * CHUNK;
    #pragma unroll
    for (int j = 0; j < CHUNK / 256; ++j) {
        int e = cb + j * 256 + threadIdx.x;
        if (e < NE) atomicAdd(&h[dst[e] >> BSH], 1);
    }
    __syncthreads();
    int* row = cntmat + (size_t)blockIdx.x * NBKT;
    for (int i = threadIdx.x; i < NBKT; i += 256) row[i] = h[i];
}

// ---- pass 2: column-wise exclusive scan -> relm[bucket][b] (transposed), btot ----
__global__ __launch_bounds__(256) void k_colscan(const int* __restrict__ cntmat,
                                                 int* __restrict__ relm,
                                                 int* __restrict__ btot) {
    __shared__ int sm[256];
    int j = blockIdx.x, t = threadIdx.x;
    int v[4];
    int b0 = t * 4;
    #pragma unroll
    for (int k = 0; k < 4; ++k) {
        int b = b0 + k;
        v[k] = (b < NPB) ? cntmat[(size_t)b * NBKT + j] : 0;
    }
    sm[t] = v[0] + v[1] + v[2] + v[3];
    __syncthreads();
    for (int off = 1; off < 256; off <<= 1) {
        int x = 0;
        if (t >= off) x = sm[t - off];
        __syncthreads();
        if (t >= off) sm[t] += x;
        __syncthreads();
    }
    int run = (t == 0) ? 0 : sm[t - 1];
    int* rrow = relm + (size_t)j * NPB;
    #pragma unroll
    for (int k = 0; k < 4; ++k) {
        int b = b0 + k;
        if (b < NPB) rrow[b] = run;
        run += v[k];
    }
    if (t == 255) btot[j] = sm[255];
}

// ---- pass 3: scan bucket totals -> boff ----
__global__ __launch_bounds__(1024) void k_scanb(const int* __restrict__ btot,
                                                int* __restrict__ boff) {
    __shared__ int sm[1024];
    int t = threadIdx.x;
    sm[t] = (t < NBKT) ? btot[t] : 0;
    __syncthreads();
    for (int off = 1; off < 1024; off <<= 1) {
        int v = 0;
        if (t >= off) v = sm[t - off];
        __syncthreads();
        if (t >= off) sm[t] += v;
        __syncthreads();
    }
    if (t < NBKT) boff[t] = t ? sm[t - 1] : 0;
    if (t == 1023) boff[NBKT] = sm[1023];   // = NE
}

// ---- pass 4: deterministic partition, single edge pass, no global atomics ----
__global__ __launch_bounds__(256) void k_part(const int* __restrict__ src,
                                              const int* __restrict__ dst,
                                              const int* __restrict__ boff,
                                              const int* __restrict__ relm,
                                              unsigned int* __restrict__ csrb) {
    __shared__ int cur[NBKT];
    int b = blockIdx.x, t = threadIdx.x;
    for (int i = t; i < NBKT; i += 256)
        cur[i] = boff[i] + relm[(size_t)i * NPB + b];
    __syncthreads();
    int cb = b * CHUNK;
    #pragma unroll
    for (int j = 0; j < CHUNK / 256; ++j) {
        int e = cb + j * 256 + t;
        if (e < NE) {
            int d = dst[e];
            int bk = d >> BSH;
            int pos = atomicAdd(&cur[bk], 1);
            csrb[pos] = (unsigned)src[e] | ((unsigned)(d & (BSPAN - 1)) << 17);
        }
    }
}

// ---- per-bucket counting sort: csrb -> csr2 (per-node order), rowptr, dinv ----
__global__ __launch_bounds__(256) void k_sortb(const int* __restrict__ boff,
                                               const unsigned int* __restrict__ csrb,
                                               int* __restrict__ csr2,
                                               int* __restrict__ rowptr,
                                               float* __restrict__ dinv) {
    __shared__ int cnt[BSPAN];
    __shared__ int sc[BSPAN];
    __shared__ int cur[BSPAN];
    int b = blockIdx.x, t = threadIdx.x;
    if (t < BSPAN) cnt[t] = 0;
    __syncthreads();
    int e0 = boff[b], e1 = boff[b + 1];
    for (int e = e0 + t; e < e1; e += 256) atomicAdd(&cnt[csrb[e] >> 17], 1);
    __syncthreads();
    if (t < BSPAN) sc[t] = cnt[t];
    __syncthreads();
    for (int off = 1; off < BSPAN; off <<= 1) {
        int v = 0;
        if (t < BSPAN && t >= off) v = sc[t - off];
        __syncthreads();
        if (t < BSPAN && t >= off) sc[t] += v;
        __syncthreads();
    }
    if (t < BSPAN) {
        int ex = e0 + (t ? sc[t - 1] : 0);
        cur[t] = ex;
        int node = b * BSPAN + t;
        if (node < NN) {
            rowptr[node] = ex;
            dinv[node] = rsqrtf((float)cnt[t] + 1.0f);
        }
    }
    if (b == 0 && t == 0) rowptr[NN] = boff[NBKT];   // = NE
    __syncthreads();
    for (int e = e0 + t; e < e1; e += 256) {
        unsigned p = csrb[e];
        int pos = atomicAdd(&cur[p >> 17], 1);
        csr2[pos] = (int)(p & 0x1FFFF);
    }
}

// ---- h1b = bf16((x @ W1) * dinv[node]) : 4 threads/node, 4 outputs each ----
__global__ __launch_bounds__(256) void k_gemm1(const float* __restrict__ x,
                                               const float* __restrict__ W1,
                                               const float* __restrict__ dinv,
                                               ushort* __restrict__ h1b) {
    __shared__ float wsm[FIN][HD];   // 8 KB
    for (int i = threadIdx.x; i < FIN * HD; i += 256) wsm[i >> 4][i & 15] = W1[i];
    __syncthreads();
    int t = blockIdx.x * 256 + threadIdx.x;
    int node = t >> 2;
    if (node >= NN) return;
    int g = (t & 3) * 4;
    const float4* xr = (const float4*)(x + (size_t)node * FIN);
    float a0 = 0.f, a1 = 0.f, a2 = 0.f, a3 = 0.f;
    #pragma unroll
    for (int k4 = 0; k4 < FIN / 4; ++k4) {
        float4 v = xr[k4];
        #pragma unroll
        for (int kk = 0; kk < 4; ++kk) {
            float vk = (kk == 0) ? v.x : (kk == 1) ? v.y : (kk == 2) ? v.z : v.w;
            float4 w = *(const float4*)&wsm[k4 * 4 + kk][g];
            a0 += vk * w.x;
            a1 += vk * w.y;
            a2 += vk * w.z;
            a3 += vk * w.w;
        }
    }
    float di = dinv[node];
    ushort4 r = {f2b(a0 * di), f2b(a1 * di), f2b(a2 * di), f2b(a3 * di)};
    *(ushort4*)(h1b + (size_t)node * HD + g) = r;
}

// ---- layer-1 aggregate + fused ReLU + fused (h2 @ W2)*dinv : wave per node ----
__global__ __launch_bounds__(256) void k_agg1(const int* __restrict__ rowptr,
                                              const int* __restrict__ csr2,
                                              const ushort* __restrict__ h1b,
                                              const float* __restrict__ dinv,
                                              const float* __restrict__ b1,
                                              const float* __restrict__ W2,
                                              float* __restrict__ g_s) {
    int wid = (blockIdx.x * 256 + threadIdx.x) >> 6;
    if (wid >= NN) return;
    int lane = threadIdx.x & 63;
    int slot = lane >> 4, f = lane & 15;
    int e0 = rowptr[wid], e1 = rowptr[wid + 1];
    float acc = 0.f, acc2 = 0.f;
    int e = e0 + slot;
    for (; e + 4 < e1; e += 8) {                 // 2 independent chains
        int s0 = csr2[e];
        int s1 = csr2[e + 4];
        acc  += bf2f(h1b[(size_t)s0 * HD + f]);
        acc2 += bf2f(h1b[(size_t)s1 * HD + f]);
    }
    if (e < e1) acc += bf2f(h1b[(size_t)csr2[e] * HD + f]);
    acc += acc2;
    acc += __shfl_xor(acc, 16, 64);
    acc += __shfl_xor(acc, 32, 64);
    if (slot == 0) {
        float di = dinv[wid];
        float v = di * (acc + bf2f(h1b[(size_t)wid * HD + f])) + b1[f];
        v = fmaxf(v, 0.f);                       // h2[wid][f], held across lanes 0..15
        float p0 = v * W2[f * 2];
        float p1 = v * W2[f * 2 + 1];
        #pragma unroll
        for (int m = 1; m <= 8; m <<= 1) {
            p0 += __shfl_xor(p0, m, 64);
            p1 += __shfl_xor(p1, m, 64);
        }
        if (f == 0) {
            float2 r = {p0 * di, p1 * di};
            *(float2*)(g_s + (size_t)wid * 2) = r;
        }
    }
}

// ---- layer-2 aggregate: one wave per node, 32 slots x 2 feats, fused softmax ----
__global__ __launch_bounds__(256) void k_agg2(const int* __restrict__ rowptr,
                                              const int* __restrict__ csr2,
                                              const float* __restrict__ g_s,
                                              const float* __restrict__ dinv,
                                              const float* __restrict__ b2,
                                              float* __restrict__ out) {
    int wid = (blockIdx.x * 256 + threadIdx.x) >> 6;
    if (wid >= NN) return;
    int lane = threadIdx.x & 63;
    int slot = lane >> 1, f = lane & 1;
    int e0 = rowptr[wid], e1 = rowptr[wid + 1];
    float acc = 0.f;
    for (int e = e0 + slot; e < e1; e += 32)
        acc += g_s[(size_t)csr2[e] * 2 + f];
    #pragma unroll
    for (int m = 2; m <= 32; m <<= 1) acc += __shfl_xor(acc, m, 64);
    if (slot == 0) {
        float di = dinv[wid];
        float o = di * (acc + g_s[(size_t)wid * 2 + f]) + b2[f];
        float other = __shfl_xor(o, 1, 64);
        float mx = fmaxf(o, other);
        float l = mx + logf(__expf(o - mx) + __expf(other - mx));
        out[(size_t)wid * 2 + f] = o - l;
    }
}

extern "C" void kernel_launch(void* const* d_in, const int* in_sizes, int n_in,
                              void* d_out, int out_size, void* d_ws, size_t ws_size,
                              hipStream_t stream) {
    const float* x   = (const float*)d_in[0];
    const int* ei    = (const int*)d_in[1];
    const int* src   = ei;
    const int* dst   = ei + NE;
    const float* W1  = (const float*)d_in[2];
    const float* b1  = (const float*)d_in[3];
    const float* W2  = (const float*)d_in[4];
    const float* b2  = (const float*)d_in[5];
    float* out = (float*)d_out;

    char* w = (char*)d_ws;
    float* dinv        = (float*)w;          w += NN * 4;
    int*   btot        = (int*)w;            w += NBKT * 4;
    int*   boff        = (int*)w;            w += (NBKT + 1) * 4;
    int*   rowptr      = (int*)w;            w += (NN + 1) * 4;
    int*   cntmat      = (int*)w;            w += (size_t)NPB * NBKT * 4;   // 2.45 MB
    int*   relm        = (int*)w;            w += (size_t)NBKT * NPB * 4;   // 2.45 MB
    unsigned int* csrb = (unsigned int*)w;   w += (size_t)NE * 4;           // 12.8 MB
    int*   csr2        = (int*)w;            w += (size_t)NE * 4;           // 12.8 MB
    ushort* h1b        = (ushort*)w;         w += (size_t)NN * HD * 2;      // 3.2 MB
    float* g_s         = (float*)w;          w += NN * CD * 4;

    k_cnt    <<<NPB, 256, 0, stream>>>(dst, cntmat);
    k_colscan<<<NBKT, 256, 0, stream>>>(cntmat, relm, btot);
    k_scanb  <<<1, 1024, 0, stream>>>(btot, boff);
    k_part   <<<NPB, 256, 0, stream>>>(src, dst, boff, relm, csrb);
    k_sortb  <<<NBKT, 256, 0, stream>>>(boff, csrb, csr2, rowptr, dinv);
    k_gemm1  <<<(NN * 4 + 255) / 256, 256, 0, stream>>>(x, W1, dinv, h1b);
    k_agg1   <<<(NN * 64 + 255) / 256, 256, 0, stream>>>(rowptr, csr2, h1b, dinv, b1, W2, g_s);
    k_agg2   <<<(NN * 64 + 255) / 256, 256, 0, stream>>>(rowptr, csr2, g_s, dinv, b2, out);
}

// Round 8
// 233.234 us; speedup vs baseline: 5.3107x; 1.2055x over previous
//
#include <hip/hip_runtime.h>
#include <hip/hip_bf16.h>

#define NN 100000
#define NE 3200000
#define FIN 128
#define HD 16
#define CD 2

#define BSH 8                        // bucket shift
#define BSPAN 256                    // nodes per bucket
#define NBKT 391                     // ceil(NN / BSPAN)
#define CHUNK 8192                   // edges per partition block
#define NPB ((NE + CHUNK - 1) / CHUNK)   // 391

__device__ __forceinline__ float bf2f(ushort u) {
    union { float f; unsigned int i; } v; v.i = ((unsigned int)u) << 16; return v.f;
}
__device__ __forceinline__ ushort f2b(float f) {
    union { float f; unsigned int u; } v; v.f = f;
    unsigned int r = (v.u + 0x7FFFu + ((v.u >> 16) & 1u)) >> 16;   // RNE
    return (ushort)r;
}

// ---- pass 1: per-block bucket counts -> cntmat[b][bucket] ----
__global__ __launch_bounds__(512) void k_cnt(const int* __restrict__ dst,
                                             int* __restrict__ cntmat) {
    __shared__ int h[NBKT];
    for (int i = threadIdx.x; i < NBKT; i += 512) h[i] = 0;
    __syncthreads();
    int cq = blockIdx.x * (CHUNK / 4);
    const int4* d4 = (const int4*)dst;
    #pragma unroll
    for (int j = 0; j < CHUNK / 2048; ++j) {
        int e4 = cq + j * 512 + threadIdx.x;
        if (e4 < NE / 4) {
            int4 d = d4[e4];
            atomicAdd(&h[d.x >> BSH], 1);
            atomicAdd(&h[d.y >> BSH], 1);
            atomicAdd(&h[d.z >> BSH], 1);
            atomicAdd(&h[d.w >> BSH], 1);
        }
    }
    __syncthreads();
    int* row = cntmat + (size_t)blockIdx.x * NBKT;
    for (int i = threadIdx.x; i < NBKT; i += 512) row[i] = h[i];
}

// ---- pass 2: column-wise exclusive scan -> relm[bucket][b], btot ----
__global__ __launch_bounds__(256) void k_colscan(const int* __restrict__ cntmat,
                                                 int* __restrict__ relm,
                                                 int* __restrict__ btot) {
    __shared__ int sm[256];
    int j = blockIdx.x, t = threadIdx.x;
    int v[2];
    int b0 = t * 2;
    #pragma unroll
    for (int k = 0; k < 2; ++k) {
        int b = b0 + k;
        v[k] = (b < NPB) ? cntmat[(size_t)b * NBKT + j] : 0;
    }
    sm[t] = v[0] + v[1];
    __syncthreads();
    for (int off = 1; off < 256; off <<= 1) {
        int x = 0;
        if (t >= off) x = sm[t - off];
        __syncthreads();
        if (t >= off) sm[t] += x;
        __syncthreads();
    }
    int run = (t == 0) ? 0 : sm[t - 1];
    int* rrow = relm + (size_t)j * NPB;
    #pragma unroll
    for (int k = 0; k < 2; ++k) {
        int b = b0 + k;
        if (b < NPB) rrow[b] = run;
        run += v[k];
    }
    if (t == 255) btot[j] = sm[255];
}

// ---- pass 3: scan bucket totals -> boff ----
__global__ __launch_bounds__(512) void k_scanb(const int* __restrict__ btot,
                                               int* __restrict__ boff) {
    __shared__ int sm[512];
    int t = threadIdx.x;
    sm[t] = (t < NBKT) ? btot[t] : 0;
    __syncthreads();
    for (int off = 1; off < 512; off <<= 1) {
        int v = 0;
        if (t >= off) v = sm[t - off];
        __syncthreads();
        if (t >= off) sm[t] += v;
        __syncthreads();
    }
    if (t < NBKT) boff[t] = t ? sm[t - 1] : 0;
    if (t == 511) boff[NBKT] = sm[511];   // = NE
}

// ---- pass 4: deterministic partition, single edge pass ----
__global__ __launch_bounds__(512) void k_part(const int* __restrict__ src,
                                              const int* __restrict__ dst,
                                              const int* __restrict__ boff,
                                              const int* __restrict__ relm,
                                              unsigned int* __restrict__ csrb) {
    __shared__ int cur[NBKT];
    int b = blockIdx.x, t = threadIdx.x;
    for (int i = t; i < NBKT; i += 512)
        cur[i] = boff[i] + relm[(size_t)i * NPB + b];
    __syncthreads();
    int cq = b * (CHUNK / 4);
    const int4* s4 = (const int4*)src;
    const int4* d4 = (const int4*)dst;
    #pragma unroll
    for (int j = 0; j < CHUNK / 2048; ++j) {
        int e4 = cq + j * 512 + t;
        if (e4 < NE / 4) {
            int4 s = s4[e4];
            int4 d = d4[e4];
            int p;
            p = atomicAdd(&cur[d.x >> BSH], 1);
            csrb[p] = (unsigned)s.x | ((unsigned)(d.x & (BSPAN - 1)) << 17);
            p = atomicAdd(&cur[d.y >> BSH], 1);
            csrb[p] = (unsigned)s.y | ((unsigned)(d.y & (BSPAN - 1)) << 17);
            p = atomicAdd(&cur[d.z >> BSH], 1);
            csrb[p] = (unsigned)s.z | ((unsigned)(d.z & (BSPAN - 1)) << 17);
            p = atomicAdd(&cur[d.w >> BSH], 1);
            csrb[p] = (unsigned)s.w | ((unsigned)(d.w & (BSPAN - 1)) << 17);
        }
    }
}

// ---- per-bucket counting sort: csrb -> csr2 (per-node order), rowptr, dinv ----
__global__ __launch_bounds__(512) void k_sortb(const int* __restrict__ boff,
                                               const unsigned int* __restrict__ csrb,
                                               int* __restrict__ csr2,
                                               int* __restrict__ rowptr,
                                               float* __restrict__ dinv) {
    __shared__ int cnt[BSPAN];
    __shared__ int sc[BSPAN];
    __shared__ int cur[BSPAN];
    int b = blockIdx.x, t = threadIdx.x;
    if (t < BSPAN) cnt[t] = 0;
    __syncthreads();
    int e0 = boff[b], e1 = boff[b + 1];
    for (int e = e0 + t; e < e1; e += 512) atomicAdd(&cnt[csrb[e] >> 17], 1);
    __syncthreads();
    if (t < BSPAN) sc[t] = cnt[t];
    __syncthreads();
    for (int off = 1; off < BSPAN; off <<= 1) {
        int v = 0;
        if (t < BSPAN && t >= off) v = sc[t - off];
        __syncthreads();
        if (t < BSPAN && t >= off) sc[t] += v;
        __syncthreads();
    }
    if (t < BSPAN) {
        int ex = e0 + (t ? sc[t - 1] : 0);
        cur[t] = ex;
        int node = b * BSPAN + t;
        if (node < NN) {
            rowptr[node] = ex;
            dinv[node] = rsqrtf((float)cnt[t] + 1.0f);
        }
    }
    if (b == 0 && t == 0) rowptr[NN] = boff[NBKT];   // = NE
    __syncthreads();
    for (int e = e0 + t; e < e1; e += 512) {
        unsigned p = csrb[e];
        int pos = atomicAdd(&cur[p >> 17], 1);
        csr2[pos] = (int)(p & 0x1FFFF);
    }
}

// ---- h1b = bf16((x @ W1) * dinv[node]) : 4 threads/node, 4 outputs each ----
__global__ __launch_bounds__(256) void k_gemm1(const float* __restrict__ x,
                                               const float* __restrict__ W1,
                                               const float* __restrict__ dinv,
                                               ushort* __restrict__ h1b) {
    __shared__ float wsm[FIN][HD];   // 8 KB
    for (int i = threadIdx.x; i < FIN * HD; i += 256) wsm[i >> 4][i & 15] = W1[i];
    __syncthreads();
    int t = blockIdx.x * 256 + threadIdx.x;
    int node = t >> 2;
    if (node >= NN) return;
    int g = (t & 3) * 4;
    const float4* xr = (const float4*)(x + (size_t)node * FIN);
    float a0 = 0.f, a1 = 0.f, a2 = 0.f, a3 = 0.f;
    #pragma unroll
    for (int k4 = 0; k4 < FIN / 4; ++k4) {
        float4 v = xr[k4];
        #pragma unroll
        for (int kk = 0; kk < 4; ++kk) {
            float vk = (kk == 0) ? v.x : (kk == 1) ? v.y : (kk == 2) ? v.z : v.w;
            float4 w = *(const float4*)&wsm[k4 * 4 + kk][g];
            a0 += vk * w.x;
            a1 += vk * w.y;
            a2 += vk * w.z;
            a3 += vk * w.w;
        }
    }
    float di = dinv[node];
    ushort4 r = {f2b(a0 * di), f2b(a1 * di), f2b(a2 * di), f2b(a3 * di)};
    *(ushort4*)(h1b + (size_t)node * HD + g) = r;
}

// ---- layer-1 aggregate + ReLU + fused (h2 @ W2)*dinv : wave per node ----
// 16 edge-slots x 4 lanes; each lane loads ushort4 (4 features)
__global__ __launch_bounds__(256) void k_agg1(const int* __restrict__ rowptr,
                                              const int* __restrict__ csr2,
                                              const ushort* __restrict__ h1b,
                                              const float* __restrict__ dinv,
                                              const float* __restrict__ b1,
                                              const float* __restrict__ W2,
                                              float* __restrict__ g_s) {
    int wid = (blockIdx.x * 256 + threadIdx.x) >> 6;
    if (wid >= NN) return;
    int lane = threadIdx.x & 63;
    int slot = lane >> 2;             // 0..15
    int fq = (lane & 3) * 4;          // 0,4,8,12
    int e0 = rowptr[wid], e1 = rowptr[wid + 1];
    float a0 = 0.f, a1 = 0.f, a2 = 0.f, a3 = 0.f;
    float c0 = 0.f, c1 = 0.f, c2 = 0.f, c3 = 0.f;
    int e = e0 + slot;
    for (; e + 16 < e1; e += 32) {                 // 2 independent chains
        int s0 = csr2[e];
        int s1 = csr2[e + 16];
        ushort4 u0 = *(const ushort4*)(h1b + (size_t)s0 * HD + fq);
        ushort4 u1 = *(const ushort4*)(h1b + (size_t)s1 * HD + fq);
        a0 += bf2f(u0.x); a1 += bf2f(u0.y); a2 += bf2f(u0.z); a3 += bf2f(u0.w);
        c0 += bf2f(u1.x); c1 += bf2f(u1.y); c2 += bf2f(u1.z); c3 += bf2f(u1.w);
    }
    if (e < e1) {
        ushort4 u = *(const ushort4*)(h1b + (size_t)csr2[e] * HD + fq);
        a0 += bf2f(u.x); a1 += bf2f(u.y); a2 += bf2f(u.z); a3 += bf2f(u.w);
    }
    a0 += c0; a1 += c1; a2 += c2; a3 += c3;
    #pragma unroll
    for (int m = 4; m <= 32; m <<= 1) {
        a0 += __shfl_xor(a0, m, 64);
        a1 += __shfl_xor(a1, m, 64);
        a2 += __shfl_xor(a2, m, 64);
        a3 += __shfl_xor(a3, m, 64);
    }
    if (slot == 0) {                  // lanes 0..3 hold features fq..fq+3
        float di = dinv[wid];
        ushort4 us = *(const ushort4*)(h1b + (size_t)wid * HD + fq);
        float v0 = fmaxf(di * (a0 + bf2f(us.x)) + b1[fq],     0.f);
        float v1 = fmaxf(di * (a1 + bf2f(us.y)) + b1[fq + 1], 0.f);
        float v2 = fmaxf(di * (a2 + bf2f(us.z)) + b1[fq + 2], 0.f);
        float v3 = fmaxf(di * (a3 + bf2f(us.w)) + b1[fq + 3], 0.f);
        float p0 = v0 * W2[fq * 2]     + v1 * W2[(fq + 1) * 2]
                 + v2 * W2[(fq + 2) * 2] + v3 * W2[(fq + 3) * 2];
        float p1 = v0 * W2[fq * 2 + 1]     + v1 * W2[(fq + 1) * 2 + 1]
                 + v2 * W2[(fq + 2) * 2 + 1] + v3 * W2[(fq + 3) * 2 + 1];
        p0 += __shfl_xor(p0, 1, 64); p0 += __shfl_xor(p0, 2, 64);
        p1 += __shfl_xor(p1, 1, 64); p1 += __shfl_xor(p1, 2, 64);
        if ((lane & 3) == 0) {
            float2 r = {p0 * di, p1 * di};
            *(float2*)(g_s + (size_t)wid * 2) = r;
        }
    }
}

// ---- layer-2 aggregate: one wave per node, 32 slots x 2 feats, fused softmax ----
__global__ __launch_bounds__(256) void k_agg2(const int* __restrict__ rowptr,
                                              const int* __restrict__ csr2,
                                              const float* __restrict__ g_s,
                                              const float* __restrict__ dinv,
                                              const float* __restrict__ b2,
                                              float* __restrict__ out) {
    int wid = (blockIdx.x * 256 + threadIdx.x) >> 6;
    if (wid >= NN) return;
    int lane = threadIdx.x & 63;
    int slot = lane >> 1, f = lane & 1;
    int e0 = rowptr[wid], e1 = rowptr[wid + 1];
    float acc = 0.f;
    for (int e = e0 + slot; e < e1; e += 32)
        acc += g_s[(size_t)csr2[e] * 2 + f];
    #pragma unroll
    for (int m = 2; m <= 32; m <<= 1) acc += __shfl_xor(acc, m, 64);
    if (slot == 0) {
        float di = dinv[wid];
        float o = di * (acc + g_s[(size_t)wid * 2 + f]) + b2[f];
        float other = __shfl_xor(o, 1, 64);
        float mx = fmaxf(o, other);
        float l = mx + logf(__expf(o - mx) + __expf(other - mx));
        out[(size_t)wid * 2 + f] = o - l;
    }
}

extern "C" void kernel_launch(void* const* d_in, const int* in_sizes, int n_in,
                              void* d_out, int out_size, void* d_ws, size_t ws_size,
                              hipStream_t stream) {
    const float* x   = (const float*)d_in[0];
    const int* ei    = (const int*)d_in[1];
    const int* src   = ei;
    const int* dst   = ei + NE;
    const float* W1  = (const float*)d_in[2];
    const float* b1  = (const float*)d_in[3];
    const float* W2  = (const float*)d_in[4];
    const float* b2  = (const float*)d_in[5];
    float* out = (float*)d_out;

    char* w = (char*)d_ws;
    float* dinv        = (float*)w;          w += NN * 4;
    int*   btot        = (int*)w;            w += NBKT * 4;
    int*   boff        = (int*)w;            w += (NBKT + 1) * 4;
    int*   rowptr      = (int*)w;            w += (NN + 1) * 4;
    int*   cntmat      = (int*)w;            w += (size_t)NPB * NBKT * 4;   // 611 KB
    int*   relm        = (int*)w;            w += (size_t)NBKT * NPB * 4;   // 611 KB
    unsigned int* csrb = (unsigned int*)w;   w += (size_t)NE * 4;           // 12.8 MB
    int*   csr2        = (int*)w;            w += (size_t)NE * 4;           // 12.8 MB
    ushort* h1b        = (ushort*)w;         w += (size_t)NN * HD * 2;      // 3.2 MB
    float* g_s         = (float*)w;          w += NN * CD * 4;

    k_cnt    <<<NPB, 512, 0, stream>>>(dst, cntmat);
    k_colscan<<<NBKT, 256, 0, stream>>>(cntmat, relm, btot);
    k_scanb  <<<1, 512, 0, stream>>>(btot, boff);
    k_part   <<<NPB, 512, 0, stream>>>(src, dst, boff, relm, csrb);
    k_sortb  <<<NBKT, 512, 0, stream>>>(boff, csrb, csr2, rowptr, dinv);
    k_gemm1  <<<(NN * 4 + 255) / 256, 256, 0, stream>>>(x, W1, dinv, h1b);
    k_agg1   <<<(NN * 64 + 255) / 256, 256, 0, stream>>>(rowptr, csr2, h1b, dinv, b1, W2, g_s);
    k_agg2   <<<(NN * 64 + 255) / 256, 256, 0, stream>>>(rowptr, csr2, g_s, dinv, b2, out);
}

// Round 9
// 210.240 us; speedup vs baseline: 5.8915x; 1.1094x over previous
//
#include <hip/hip_runtime.h>
#include <hip/hip_bf16.h>

#define NN 100000
#define NE 3200000
#define FIN 128
#define HD 16
#define CD 2

#define BSH 8                        // bucket shift
#define BSPAN 256                    // nodes per bucket
#define NBKT 391                     // ceil(NN / BSPAN)
#define CHUNK 8192                   // edges per partition block
#define NPB ((NE + CHUNK - 1) / CHUNK)   // 391

__device__ __forceinline__ float bf2f(ushort u) {
    union { float f; unsigned int i; } v; v.i = ((unsigned int)u) << 16; return v.f;
}
__device__ __forceinline__ ushort f2b(float f) {
    union { float f; unsigned int u; } v; v.f = f;
    unsigned int r = (v.u + 0x7FFFu + ((v.u >> 16) & 1u)) >> 16;   // RNE
    return (ushort)r;
}

// ---- pass 1: per-block bucket counts -> cntmat[b][bucket] ----
__global__ __launch_bounds__(512) void k_cnt(const int* __restrict__ dst,
                                             int* __restrict__ cntmat) {
    __shared__ int h[NBKT];
    for (int i = threadIdx.x; i < NBKT; i += 512) h[i] = 0;
    __syncthreads();
    int cq = blockIdx.x * (CHUNK / 4);
    const int4* d4 = (const int4*)dst;
    #pragma unroll
    for (int j = 0; j < CHUNK / 2048; ++j) {
        int e4 = cq + j * 512 + threadIdx.x;
        if (e4 < NE / 4) {
            int4 d = d4[e4];
            atomicAdd(&h[d.x >> BSH], 1);
            atomicAdd(&h[d.y >> BSH], 1);
            atomicAdd(&h[d.z >> BSH], 1);
            atomicAdd(&h[d.w >> BSH], 1);
        }
    }
    __syncthreads();
    int* row = cntmat + (size_t)blockIdx.x * NBKT;
    for (int i = threadIdx.x; i < NBKT; i += 512) row[i] = h[i];
}

// ---- pass 2: column-wise exclusive scan -> relm[bucket][b], btot ----
__global__ __launch_bounds__(256) void k_colscan(const int* __restrict__ cntmat,
                                                 int* __restrict__ relm,
                                                 int* __restrict__ btot) {
    __shared__ int sm[256];
    int j = blockIdx.x, t = threadIdx.x;
    int v[2];
    int b0 = t * 2;
    #pragma unroll
    for (int k = 0; k < 2; ++k) {
        int b = b0 + k;
        v[k] = (b < NPB) ? cntmat[(size_t)b * NBKT + j] : 0;
    }
    sm[t] = v[0] + v[1];
    __syncthreads();
    for (int off = 1; off < 256; off <<= 1) {
        int x = 0;
        if (t >= off) x = sm[t - off];
        __syncthreads();
        if (t >= off) sm[t] += x;
        __syncthreads();
    }
    int run = (t == 0) ? 0 : sm[t - 1];
    int* rrow = relm + (size_t)j * NPB;
    #pragma unroll
    for (int k = 0; k < 2; ++k) {
        int b = b0 + k;
        if (b < NPB) rrow[b] = run;
        run += v[k];
    }
    if (t == 255) btot[j] = sm[255];
}

// ---- pass 3: scan bucket totals -> boff ----
__global__ __launch_bounds__(512) void k_scanb(const int* __restrict__ btot,
                                               int* __restrict__ boff) {
    __shared__ int sm[512];
    int t = threadIdx.x;
    sm[t] = (t < NBKT) ? btot[t] : 0;
    __syncthreads();
    for (int off = 1; off < 512; off <<= 1) {
        int v = 0;
        if (t >= off) v = sm[t - off];
        __syncthreads();
        if (t >= off) sm[t] += v;
        __syncthreads();
    }
    if (t < NBKT) boff[t] = t ? sm[t - 1] : 0;
    if (t == 511) boff[NBKT] = sm[511];   // = NE
}

// ---- pass 4: deterministic partition, single edge pass ----
__global__ __launch_bounds__(512) void k_part(const int* __restrict__ src,
                                              const int* __restrict__ dst,
                                              const int* __restrict__ boff,
                                              const int* __restrict__ relm,
                                              unsigned int* __restrict__ csrb) {
    __shared__ int cur[NBKT];
    int b = blockIdx.x, t = threadIdx.x;
    for (int i = t; i < NBKT; i += 512)
        cur[i] = boff[i] + relm[(size_t)i * NPB + b];
    __syncthreads();
    int cq = b * (CHUNK / 4);
    const int4* s4 = (const int4*)src;
    const int4* d4 = (const int4*)dst;
    #pragma unroll
    for (int j = 0; j < CHUNK / 2048; ++j) {
        int e4 = cq + j * 512 + t;
        if (e4 < NE / 4) {
            int4 s = s4[e4];
            int4 d = d4[e4];
            int p;
            p = atomicAdd(&cur[d.x >> BSH], 1);
            csrb[p] = (unsigned)s.x | ((unsigned)(d.x & (BSPAN - 1)) << 17);
            p = atomicAdd(&cur[d.y >> BSH], 1);
            csrb[p] = (unsigned)s.y | ((unsigned)(d.y & (BSPAN - 1)) << 17);
            p = atomicAdd(&cur[d.z >> BSH], 1);
            csrb[p] = (unsigned)s.z | ((unsigned)(d.z & (BSPAN - 1)) << 17);
            p = atomicAdd(&cur[d.w >> BSH], 1);
            csrb[p] = (unsigned)s.w | ((unsigned)(d.w & (BSPAN - 1)) << 17);
        }
    }
}

// ---- per-bucket counting sort: csrb -> csr2 (per-node order), rowptr, dinv ----
__global__ __launch_bounds__(512) void k_sortb(const int* __restrict__ boff,
                                               const unsigned int* __restrict__ csrb,
                                               int* __restrict__ csr2,
                                               int* __restrict__ rowptr,
                                               float* __restrict__ dinv) {
    __shared__ int cnt[BSPAN];
    __shared__ int sc[BSPAN];
    __shared__ int cur[BSPAN];
    int b = blockIdx.x, t = threadIdx.x;
    if (t < BSPAN) cnt[t] = 0;
    __syncthreads();
    int e0 = boff[b], e1 = boff[b + 1];
    for (int e = e0 + t; e < e1; e += 512) atomicAdd(&cnt[csrb[e] >> 17], 1);
    __syncthreads();
    if (t < BSPAN) sc[t] = cnt[t];
    __syncthreads();
    for (int off = 1; off < BSPAN; off <<= 1) {
        int v = 0;
        if (t < BSPAN && t >= off) v = sc[t - off];
        __syncthreads();
        if (t < BSPAN && t >= off) sc[t] += v;
        __syncthreads();
    }
    if (t < BSPAN) {
        int ex = e0 + (t ? sc[t - 1] : 0);
        cur[t] = ex;
        int node = b * BSPAN + t;
        if (node < NN) {
            rowptr[node] = ex;
            dinv[node] = rsqrtf((float)cnt[t] + 1.0f);
        }
    }
    if (b == 0 && t == 0) rowptr[NN] = boff[NBKT];   // = NE
    __syncthreads();
    for (int e = e0 + t; e < e1; e += 512) {
        unsigned p = csrb[e];
        int pos = atomicAdd(&cur[p >> 17], 1);
        csr2[pos] = (int)(p & 0x1FFFF);
    }
}

// ---- h1b = bf16((x @ W1) * dinv[node]) : 4 threads/node, 4 outputs each ----
__global__ __launch_bounds__(256) void k_gemm1(const float* __restrict__ x,
                                               const float* __restrict__ W1,
                                               const float* __restrict__ dinv,
                                               ushort* __restrict__ h1b) {
    __shared__ float wsm[FIN][HD];   // 8 KB
    for (int i = threadIdx.x; i < FIN * HD; i += 256) wsm[i >> 4][i & 15] = W1[i];
    __syncthreads();
    int t = blockIdx.x * 256 + threadIdx.x;
    int node = t >> 2;
    if (node >= NN) return;
    int g = (t & 3) * 4;
    const float4* xr = (const float4*)(x + (size_t)node * FIN);
    float a0 = 0.f, a1 = 0.f, a2 = 0.f, a3 = 0.f;
    #pragma unroll
    for (int k4 = 0; k4 < FIN / 4; ++k4) {
        float4 v = xr[k4];
        #pragma unroll
        for (int kk = 0; kk < 4; ++kk) {
            float vk = (kk == 0) ? v.x : (kk == 1) ? v.y : (kk == 2) ? v.z : v.w;
            float4 w = *(const float4*)&wsm[k4 * 4 + kk][g];
            a0 += vk * w.x;
            a1 += vk * w.y;
            a2 += vk * w.z;
            a3 += vk * w.w;
        }
    }
    float di = dinv[node];
    ushort4 r = {f2b(a0 * di), f2b(a1 * di), f2b(a2 * di), f2b(a3 * di)};
    *(ushort4*)(h1b + (size_t)node * HD + g) = r;
}

// ---- layer-1 aggregate + ReLU + fused (h2 @ W2)*dinv : 4 nodes per wave ----
// 16 lanes/node: 4 edge-slots x 4 lanes; each lane loads ushort4 (4 features)
__global__ __launch_bounds__(256) void k_agg1(const int* __restrict__ rowptr,
                                              const int* __restrict__ csr2,
                                              const ushort* __restrict__ h1b,
                                              const float* __restrict__ dinv,
                                              const float* __restrict__ b1,
                                              const float* __restrict__ W2,
                                              float* __restrict__ g_s) {
    int wid = (blockIdx.x * 256 + threadIdx.x) >> 6;
    int lane = threadIdx.x & 63;
    int node = wid * 4 + (lane >> 4);
    if (node >= NN) return;
    int l16 = lane & 15;
    int slot = l16 >> 2;              // 0..3
    int fq = (lane & 3) * 4;          // 0,4,8,12
    int e0 = rowptr[node], e1 = rowptr[node + 1];
    float a0 = 0.f, a1 = 0.f, a2 = 0.f, a3 = 0.f;
    float c0 = 0.f, c1 = 0.f, c2 = 0.f, c3 = 0.f;
    int e = e0 + slot;
    for (; e + 4 < e1; e += 8) {                 // 2 independent chains
        int s0 = csr2[e];
        int s1 = csr2[e + 4];
        ushort4 u0 = *(const ushort4*)(h1b + (size_t)s0 * HD + fq);
        ushort4 u1 = *(const ushort4*)(h1b + (size_t)s1 * HD + fq);
        a0 += bf2f(u0.x); a1 += bf2f(u0.y); a2 += bf2f(u0.z); a3 += bf2f(u0.w);
        c0 += bf2f(u1.x); c1 += bf2f(u1.y); c2 += bf2f(u1.z); c3 += bf2f(u1.w);
    }
    if (e < e1) {
        ushort4 u = *(const ushort4*)(h1b + (size_t)csr2[e] * HD + fq);
        a0 += bf2f(u.x); a1 += bf2f(u.y); a2 += bf2f(u.z); a3 += bf2f(u.w);
    }
    a0 += c0; a1 += c1; a2 += c2; a3 += c3;
    // reduce across the 4 slots (xor 4, 8 stays within the 16-lane node group)
    #pragma unroll
    for (int m = 4; m <= 8; m <<= 1) {
        a0 += __shfl_xor(a0, m, 64);
        a1 += __shfl_xor(a1, m, 64);
        a2 += __shfl_xor(a2, m, 64);
        a3 += __shfl_xor(a3, m, 64);
    }
    if (slot == 0) {                  // lanes l16=0..3 hold features fq..fq+3
        float di = dinv[node];
        ushort4 us = *(const ushort4*)(h1b + (size_t)node * HD + fq);
        float v0 = fmaxf(di * (a0 + bf2f(us.x)) + b1[fq],     0.f);
        float v1 = fmaxf(di * (a1 + bf2f(us.y)) + b1[fq + 1], 0.f);
        float v2 = fmaxf(di * (a2 + bf2f(us.z)) + b1[fq + 2], 0.f);
        float v3 = fmaxf(di * (a3 + bf2f(us.w)) + b1[fq + 3], 0.f);
        float p0 = v0 * W2[fq * 2]       + v1 * W2[(fq + 1) * 2]
                 + v2 * W2[(fq + 2) * 2] + v3 * W2[(fq + 3) * 2];
        float p1 = v0 * W2[fq * 2 + 1]       + v1 * W2[(fq + 1) * 2 + 1]
                 + v2 * W2[(fq + 2) * 2 + 1] + v3 * W2[(fq + 3) * 2 + 1];
        p0 += __shfl_xor(p0, 1, 64); p0 += __shfl_xor(p0, 2, 64);
        p1 += __shfl_xor(p1, 1, 64); p1 += __shfl_xor(p1, 2, 64);
        if (l16 == 0) {
            float2 r = {p0 * di, p1 * di};
            *(float2*)(g_s + (size_t)node * 2) = r;
        }
    }
}

// ---- layer-2 aggregate: 4 nodes per wave, 8 slots x 2 feats, fused softmax ----
__global__ __launch_bounds__(256) void k_agg2(const int* __restrict__ rowptr,
                                              const int* __restrict__ csr2,
                                              const float* __restrict__ g_s,
                                              const float* __restrict__ dinv,
                                              const float* __restrict__ b2,
                                              float* __restrict__ out) {
    int wid = (blockIdx.x * 256 + threadIdx.x) >> 6;
    int lane = threadIdx.x & 63;
    int node = wid * 4 + (lane >> 4);
    if (node >= NN) return;
    int l16 = lane & 15;
    int slot = l16 >> 1, f = lane & 1;
    int e0 = rowptr[node], e1 = rowptr[node + 1];
    float acc = 0.f;
    for (int e = e0 + slot; e < e1; e += 8)
        acc += g_s[(size_t)csr2[e] * 2 + f];
    #pragma unroll
    for (int m = 2; m <= 8; m <<= 1) acc += __shfl_xor(acc, m, 64);
    if (slot == 0) {                  // lanes l16=0,1
        float di = dinv[node];
        float o = di * (acc + g_s[(size_t)node * 2 + f]) + b2[f];
        float other = __shfl_xor(o, 1, 64);
        float mx = fmaxf(o, other);
        float l = mx + logf(__expf(o - mx) + __expf(other - mx));
        out[(size_t)node * 2 + f] = o - l;
    }
}

extern "C" void kernel_launch(void* const* d_in, const int* in_sizes, int n_in,
                              void* d_out, int out_size, void* d_ws, size_t ws_size,
                              hipStream_t stream) {
    const float* x   = (const float*)d_in[0];
    const int* ei    = (const int*)d_in[1];
    const int* src   = ei;
    const int* dst   = ei + NE;
    const float* W1  = (const float*)d_in[2];
    const float* b1  = (const float*)d_in[3];
    const float* W2  = (const float*)d_in[4];
    const float* b2  = (const float*)d_in[5];
    float* out = (float*)d_out;

    char* w = (char*)d_ws;
    float* dinv        = (float*)w;          w += NN * 4;
    int*   btot        = (int*)w;            w += NBKT * 4;
    int*   boff        = (int*)w;            w += (NBKT + 1) * 4;
    int*   rowptr      = (int*)w;            w += (NN + 1) * 4;
    int*   cntmat      = (int*)w;            w += (size_t)NPB * NBKT * 4;   // 611 KB
    int*   relm        = (int*)w;            w += (size_t)NBKT * NPB * 4;   // 611 KB
    unsigned int* csrb = (unsigned int*)w;   w += (size_t)NE * 4;           // 12.8 MB
    int*   csr2        = (int*)w;            w += (size_t)NE * 4;           // 12.8 MB
    ushort* h1b        = (ushort*)w;         w += (size_t)NN * HD * 2;      // 3.2 MB
    float* g_s         = (float*)w;          w += NN * CD * 4;

    k_cnt    <<<NPB, 512, 0, stream>>>(dst, cntmat);
    k_colscan<<<NBKT, 256, 0, stream>>>(cntmat, relm, btot);
    k_scanb  <<<1, 512, 0, stream>>>(btot, boff);
    k_part   <<<NPB, 512, 0, stream>>>(src, dst, boff, relm, csrb);
    k_sortb  <<<NBKT, 512, 0, stream>>>(boff, csrb, csr2, rowptr, dinv);
    k_gemm1  <<<(NN * 4 + 255) / 256, 256, 0, stream>>>(x, W1, dinv, h1b);
    k_agg1   <<<(NN * 16 + 255) / 256, 256, 0, stream>>>(rowptr, csr2, h1b, dinv, b1, W2, g_s);
    k_agg2   <<<(NN * 16 + 255) / 256, 256, 0, stream>>>(rowptr, csr2, g_s, dinv, b2, out);
}